// Round 6
// baseline (262.351 us; speedup 1.0000x reference)
//
#include <hip/hip_runtime.h>

// SDGCN fused: per (b,t): S=X·X^T, softmax (diag-shift c_r=||x_r||^2, linear Z),
// A-mask, H=(A*P/Z*c_a)·X, relu(H·W^T)*c_b, LayerNorm, +X residual. bf16 MFMA.
// R10: R9 fixed the spill (WRITE back to 32.8MB=output) but VALU (32%) is the
//      top pipe: hand-rolled f2bf = 4 VALU/value; W-epilogue alone converts
//      256 values/wave (~1000 ops). Two independent fixes:
//  (1) v_cvt_pk_bf16_f32 (2 values/instr, T12 recipe) at pack8 / staging /
//      softmax-P sites -> ~8x fewer conversion VALU ops.
//  (2) subtile stride 128B -> 136B: QK b128 reads were 8-way bank-conflicted
//      (subtile index contributed 0 mod 32 banks); 136B rotates banks by 2s
//      -> 4-way. tr-read lane addrs stay 8B-aligned (136s ≡ 0 mod 8; R8
//      established the contiguous-per-lane model, R5's bug was 2B-granular
//      addresses, not stride padding). Staging/tr-read conflict unchanged.
//  (carried) packed-subtile X double-buffer, 1 barrier/chunk, tr-read PV with
//  waitcnt inside asm (R7), named tr outputs + mid-body staging write (R9).

#define NNODES 1024
#define DDIM   128
#define BROWS  128           // rows per block
#define WROWS  16            // rows per wave
#define MC     64            // m-chunk
#define NCHUNK (NNODES / MC) // 16
#define THREADS 512

#define CA 0.08838834764831845f   // 1/sqrt(128+1e-8)
#define CB 0.08838834764831845f   // 1/sqrt(128+1e-9)
#define LN_EPS 1e-5f

typedef __attribute__((ext_vector_type(8))) short bf16x8;
typedef __attribute__((ext_vector_type(4))) float f32x4;
typedef __attribute__((ext_vector_type(2))) unsigned int u32x2;

// X-chunk subtile s = (d>>4)*16 + (m>>2); inner [4m][16d] bf16 row-major.
// Stride 68 ushorts = 136B: 128B data + 8B pad -> bank rotation 2s.
#define STILE(s) (68*(s))

// LDS layout (ushort units)
#define XB0_OFF 0                 // X-chunk buffer 0: 8704 ushorts
#define XB1_OFF 8704              // X-chunk buffer 1: 8704 ushorts
#define P_OFF   17408             // P per wave [16][72], col-swizzled: 9216
#define P_S     72
#define H_S     136               // h tile reuses [0,17408) after main loop
#define SM_TOT  26624             // 53248 bytes -> 2 blocks/CU

// 8 tr-reads (4 dt x {lo,hi}) + internal drain. Lane addr = contiguous 8B in
// the 16-lane group's 136B-strided subtile; offsets dt*2176 + {0,136}.
#define TRREAD8(T0,T1,T2,T3,T4,T5,T6,T7, AP)                                \
  asm volatile(                                                             \
    "ds_read_b64_tr_b16 %0, %8 offset:0\n\t"                                \
    "ds_read_b64_tr_b16 %1, %8 offset:136\n\t"                              \
    "ds_read_b64_tr_b16 %2, %8 offset:2176\n\t"                             \
    "ds_read_b64_tr_b16 %3, %8 offset:2312\n\t"                             \
    "ds_read_b64_tr_b16 %4, %8 offset:4352\n\t"                             \
    "ds_read_b64_tr_b16 %5, %8 offset:4488\n\t"                             \
    "ds_read_b64_tr_b16 %6, %8 offset:6528\n\t"                             \
    "ds_read_b64_tr_b16 %7, %8 offset:6664\n\t"                             \
    "s_waitcnt lgkmcnt(0)"                                                  \
    : "=&v"(T0), "=&v"(T1), "=&v"(T2), "=&v"(T3),                           \
      "=&v"(T4), "=&v"(T5), "=&v"(T6), "=&v"(T7)                            \
    : "v"(AP))

__device__ __forceinline__ unsigned int cvt_pk(float lo, float hi) {
  unsigned int r;
  asm("v_cvt_pk_bf16_f32 %0, %1, %2" : "=v"(r) : "v"(lo), "v"(hi));
  return r;
}

__device__ __forceinline__ unsigned short f2bf(float f) {
  unsigned int u = __float_as_uint(f);
  u += 0x7FFFu + ((u >> 16) & 1u);     // RNE
  return (unsigned short)(u >> 16);
}

__device__ __forceinline__ bf16x8 pack8(float4 a, float4 b) {
  union { unsigned int w[4]; bf16x8 v; } u;
  u.w[0] = cvt_pk(a.x, a.y); u.w[1] = cvt_pk(a.z, a.w);
  u.w[2] = cvt_pk(b.x, b.y); u.w[3] = cvt_pk(b.z, b.w);
  return u.v;
}

__device__ __forceinline__ bf16x8 joinpair(u32x2 lo, u32x2 hi) {
  union { u32x2 d[2]; bf16x8 v; } u;
  u.d[0] = lo; u.d[1] = hi;
  return u.v;
}

__global__ __launch_bounds__(THREADS, 4)
void sdgcn_fused(const float* __restrict__ X, const float* __restrict__ A,
                 const float* __restrict__ W, const float* __restrict__ gamma,
                 const float* __restrict__ beta, float* __restrict__ Out) {
  const int bt   = blockIdx.x;                 // fast axis: blocks sharing A-slice adjacent
  const int row0 = blockIdx.y * BROWS;
  const int tid  = (int)threadIdx.x;
  const int wid  = tid >> 6;      // wave id 0..7
  const int lane = tid & 63;
  const int c    = lane & 15;     // 16-dim index within MFMA tile
  const int q    = lane >> 4;     // quad 0..3
  const int c2 = c >> 2, c3 = c & 3, q1 = q & 1, q2 = q >> 1;

  const float* Xbt = X + (size_t)bt * NNODES * DDIM;

  __shared__ __align__(128) unsigned short sm[SM_TOT];
  unsigned short* Pw = sm + P_OFF + wid * (WROWS * P_S);

  // P col-swizzle: element [row=query c][col m] stored at col ^ pswz(row).
  const int pswz = 16 * ((c >> 3) & 1);

  // ---- Q A-fragments + query sum-of-squares (fp32, LANE-LOCAL: query = c) ----
  bf16x8 qfrag[4];
  float ss = 0.f;                // ss = ||x_{query c}||^2 (diag softmax shift)
  {
    const float* qrow = Xbt + (size_t)(row0 + wid * WROWS + c) * DDIM;
#pragma unroll
    for (int ds = 0; ds < 4; ++ds) {
      const float* p = qrow + ds * 32 + q * 8;
      float4 a = *(const float4*)p;
      float4 b = *(const float4*)(p + 4);
      ss += a.x*a.x + a.y*a.y + a.z*a.z + a.w*a.w;
      ss += b.x*b.x + b.y*b.y + b.z*b.z + b.w*b.w;
      qfrag[ds] = pack8(a, b);
    }
    ss += __shfl_xor(ss, 16, 64);
    ss += __shfl_xor(ss, 32, 64);
  }

  float z_acc = 0.f;   // per-lane partial Z for query c (reduced at end)
  f32x4 Ofr[8];   // O accumulator, C/D layout: row(query)=4q+reg, col=dt*16+c
#pragma unroll
  for (int dt = 0; dt < 8; ++dt) Ofr[dt] = (f32x4){0.f, 0.f, 0.f, 0.f};

  const int grow = row0 + wid * WROWS + q * 4;   // +r gives global row for C/D rows
  const int arow = row0 + wid * WROWS + c;       // query row for A-mask / softmax

  // ---- staging map: thread -> (m = mlo + 4*(mh0+4k), float4 col sd4) ----
  const int h4  = tid & 15;
  const int mlo = (tid >> 4) & 3;          // m & 3
  const int sd4 = h4 + 16 * (wid & 1);     // float4 column 0..31
  const int mh0 = wid >> 1;                // m>>2 = mh0 + 4k
  const int sst = (sd4 >> 2) * 16 + mh0;   // subtile for k=0; +4k for others
  const int sof = 16*mlo + 4*(sd4 & 3);    // intra-subtile ushort offset

  // ---- prologue: chunk 0 -> buf0 (visible after loop's first barrier) ----
  {
    float4 stg[4];
#pragma unroll
    for (int k = 0; k < 4; ++k)
      stg[k] = *(const float4*)(Xbt + (size_t)(mlo + 4*(mh0 + 4*k)) * DDIM + sd4 * 4);
#pragma unroll
    for (int k = 0; k < 4; ++k) {
      float4 v = stg[k];
      *(uint2*)(sm + XB0_OFF + STILE(sst + 4*k) + sof) =
          make_uint2(cvt_pk(v.x, v.y), cvt_pk(v.z, v.w));
    }
  }

  for (int ch = 0; ch < NCHUNK; ++ch) {
    const int m0 = ch * MC;
    unsigned short* xb  = sm + ((ch & 1) ? XB1_OFF : XB0_OFF);
    unsigned short* xbn = sm + ((ch & 1) ? XB0_OFF : XB1_OFF);
    // tr-read lane base: contiguous per-lane 8B; subtile 2q at +272B, lane c at +8c.
    const unsigned trb = (unsigned)(size_t)xb + 272u*q + 8u*c;

    __syncthreads();   // xb ready; xbn free (its ch-1 readers all arrived here)

    // ---- issue next chunk's staging loads (wait hides under QK) ----
    float4 stg[4];
    if (ch + 1 < NCHUNK) {
      const float* nx = Xbt + (size_t)(m0 + MC) * DDIM;
#pragma unroll
      for (int k = 0; k < 4; ++k)
        stg[k] = *(const float4*)(nx + (size_t)(mlo + 4*(mh0 + 4*k)) * DDIM + sd4 * 4);
    }
    // ---- prefetch adjacency row (float4; query row = c, cols 16mt+4q+r) ----
    float4 av[4];
#pragma unroll
    for (int mt = 0; mt < 4; ++mt)
      av[mt] = *(const float4*)(A + (size_t)arow * NNODES + m0 + mt*16 + 4*q);
    // ---- scores S^T = mfma(X-rows, Q): C/D row = m (16mt+4q+r), col = query c
    f32x4 S[4];
#pragma unroll
    for (int mt = 0; mt < 4; ++mt) {
      f32x4 acc = (f32x4){0.f, 0.f, 0.f, 0.f};
#pragma unroll
      for (int ds = 0; ds < 4; ++ds) {
        const bf16x8 bf = *(const bf16x8*)(xb + STILE((ds*2 + q2)*16 + mt*4 + c2)
                                              + 16*c3 + 8*q1);
        acc = __builtin_amdgcn_mfma_f32_16x16x32_bf16(bf, qfrag[ds], acc, 0, 0, 0);
      }
      S[mt] = acc;
    }
    // ---- convert + write next chunk into xbn (stg dies here, mid-body) ----
    if (ch + 1 < NCHUNK) {
#pragma unroll
      for (int k = 0; k < 4; ++k) {
        float4 v = stg[k];
        *(uint2*)(xbn + STILE(sst + 4*k) + sof) =
            make_uint2(cvt_pk(v.x, v.y), cvt_pk(v.z, v.w));
      }
    }
    // ---- softmax numerator (lane-local query): p = exp(S^T - ss);
    //      P[query c][m] written as uint2 4-runs, col ^ pswz ----
    float zr = 0.f;
#pragma unroll
    for (int mt = 0; mt < 4; ++mt) {
      float p0 = __expf(S[mt][0] - ss);
      float p1 = __expf(S[mt][1] - ss);
      float p2 = __expf(S[mt][2] - ss);
      float p3 = __expf(S[mt][3] - ss);
      zr += (p0 + p1) + (p2 + p3);
      *(uint2*)(Pw + c * P_S + ((mt*16 + 4*q) ^ pswz)) =
          make_uint2(cvt_pk(p0 * av[mt].x, p1 * av[mt].y),
                     cvt_pk(p2 * av[mt].z, p3 * av[mt].w));
    }
    z_acc += zr;
    // ---- PV: O += P·Xchunk ; A=P rows (b128, swizzle-corrected), B via HW
    //      transpose-read: 2 batches of 8 per ks, drain inside each asm ----
#pragma unroll
    for (int ks = 0; ks < 2; ++ks) {
      const bf16x8 pf = *(const bf16x8*)(Pw + c * P_S + ((ks*32 + q*8) ^ pswz));
      u32x2 t0, t1, t2, t3, t4, t5, t6, t7;
      TRREAD8(t0, t1, t2, t3, t4, t5, t6, t7, trb + 1088u*ks);
      Ofr[0] = __builtin_amdgcn_mfma_f32_16x16x32_bf16(pf, joinpair(t0, t1), Ofr[0], 0, 0, 0);
      Ofr[1] = __builtin_amdgcn_mfma_f32_16x16x32_bf16(pf, joinpair(t2, t3), Ofr[1], 0, 0, 0);
      Ofr[2] = __builtin_amdgcn_mfma_f32_16x16x32_bf16(pf, joinpair(t4, t5), Ofr[2], 0, 0, 0);
      Ofr[3] = __builtin_amdgcn_mfma_f32_16x16x32_bf16(pf, joinpair(t6, t7), Ofr[3], 0, 0, 0);
      TRREAD8(t0, t1, t2, t3, t4, t5, t6, t7, trb + 1088u*ks + 8704u);
      Ofr[4] = __builtin_amdgcn_mfma_f32_16x16x32_bf16(pf, joinpair(t0, t1), Ofr[4], 0, 0, 0);
      Ofr[5] = __builtin_amdgcn_mfma_f32_16x16x32_bf16(pf, joinpair(t2, t3), Ofr[5], 0, 0, 0);
      Ofr[6] = __builtin_amdgcn_mfma_f32_16x16x32_bf16(pf, joinpair(t4, t5), Ofr[6], 0, 0, 0);
      Ofr[7] = __builtin_amdgcn_mfma_f32_16x16x32_bf16(pf, joinpair(t6, t7), Ofr[7], 0, 0, 0);
    }
  }

  // ---- finalize Z: reduce q-group partials, then broadcast to C/D rows ----
  z_acc += __shfl_xor(z_acc, 16, 64);
  z_acc += __shfl_xor(z_acc, 32, 64);
  float zrow[4];
#pragma unroll
  for (int r = 0; r < 4; ++r)
    zrow[r] = __shfl(z_acc, (lane & 48) + ((lane & 48) >> 2) + r, 64);

  __syncthreads();   // all PV reads done; reuse X/P region for h
  // ---- h = (CA/z)*O -> bf16, per-wave LDS round-trip into A-layout (swizzled) ----
  unsigned short* Hw = sm + wid * (WROWS * H_S);
#pragma unroll
  for (int r = 0; r < 4; ++r) {
    float rinv = CA / zrow[r];
#pragma unroll
    for (int dt = 0; dt < 8; ++dt)
      Hw[(q*4 + r) * H_S + (((dt*16) ^ (16*(q>>1))) + c)] = f2bf(Ofr[dt][r] * rinv);
  }
  // ---- G = h·W^T via MFMA; B[k=d][j] = W row-reads direct from global ----
  f32x4 G[8];
#pragma unroll
  for (int jt = 0; jt < 8; ++jt) G[jt] = (f32x4){0.f, 0.f, 0.f, 0.f};
#pragma unroll
  for (int ks = 0; ks < 4; ++ks) {
    bf16x8 hf = *(const bf16x8*)(Hw + c * H_S + ((ks*32 + q*8) ^ pswz));
#pragma unroll
    for (int jt = 0; jt < 8; ++jt) {
      const float* wr = W + (size_t)(jt*16 + c) * DDIM + ks*32 + q*8;
      float4 a = *(const float4*)wr;
      float4 b = *(const float4*)(wr + 4);
      bf16x8 wf = pack8(a, b);
      G[jt] = __builtin_amdgcn_mfma_f32_16x16x32_bf16(hf, wf, G[jt], 0, 0, 0);
    }
  }
  // relu + output scale
#pragma unroll
  for (int jt = 0; jt < 8; ++jt) {
#pragma unroll
    for (int r = 0; r < 4; ++r) G[jt][r] = fmaxf(G[jt][r], 0.f) * CB;
  }
  // ---- LayerNorm over j (in-reg jt sum + 16-lane shfl), + residual, store ----
  float* Obt = Out + (size_t)bt * NNODES * DDIM;
#pragma unroll
  for (int r = 0; r < 4; ++r) {
    float s1 = 0.f, s2 = 0.f;
#pragma unroll
    for (int jt = 0; jt < 8; ++jt) { float v = G[jt][r]; s1 += v; s2 += v * v; }
#pragma unroll
    for (int off = 1; off < 16; off <<= 1) {
      s1 += __shfl_xor(s1, off, 64);
      s2 += __shfl_xor(s2, off, 64);
    }
    float mu = s1 * (1.f / 128.f);
    float va = s2 * (1.f / 128.f) - mu * mu;
    float rs = rsqrtf(va + LN_EPS);
    const float* xr = Xbt + (size_t)(grow + r) * DDIM;
    float* orow = Obt + (size_t)(grow + r) * DDIM;
#pragma unroll
    for (int jt = 0; jt < 8; ++jt) {
      int col = jt * 16 + c;
      orow[col] = (G[jt][r] - mu) * rs * gamma[col] + beta[col] + xr[col];
    }
  }
}

extern "C" void kernel_launch(void* const* d_in, const int* in_sizes, int n_in,
                              void* d_out, int out_size, void* d_ws, size_t ws_size,
                              hipStream_t stream) {
  const float* X     = (const float*)d_in[0];
  const float* A     = (const float*)d_in[1];
  const float* W     = (const float*)d_in[2];
  const float* gamma = (const float*)d_in[3];
  const float* beta  = (const float*)d_in[4];
  float* Out = (float*)d_out;
  dim3 grid(64, NNODES / BROWS);   // bt fast, 8 row-blocks slow
  hipLaunchKernelGGL(sdgcn_fused, grid, dim3(THREADS), 0, stream, X, A, W, gamma, beta, Out);
}

// Round 7
// 173.454 us; speedup vs baseline: 1.5125x; 1.5125x over previous
//
#include <hip/hip_runtime.h>
#include <hip/hip_bf16.h>

// SDGCN fused: per (b,t): S=X·X^T, softmax (diag-shift c_r=||x_r||^2, linear Z),
// A-mask, H=(A*P/Z*c_a)·X, relu(H·W^T)*c_b, LayerNorm, +X residual. bf16 MFMA.
// R11: R10 regressed (195us): inline-asm cvt_pk pinned VGPRs -> spill returned
//      (WRITE 32.8->69MB, VGPR 60->64). The guide's m240 note said exactly
//      this: "inline-asm cvt_pk -37% vs scalar cast - compiler handles it".
//      R11 = exact R9 structure/layout + paired conversions via
//      __float22bfloat162_rn (plain dataflow, lowers to v_cvt_pk_bf16_f32,
//      RNE): staging pairs, softmax-P pairs, pack8 (qfrag + W epilogue).
//      Scattered scalar Hw writes keep integer f2bf. Stride back to 128B
//      (R9-identical LDS map; stride-136 untested separately, not re-risked).
//  (carried from R9) packed [4m][16d] subtiles, X double-buffer, 1 barrier/
//  chunk; S^T lane-local softmax; TRREAD8 named outputs with waitcnt inside;
//  mid-body staging write (stg dies before PV).

#define NNODES 1024
#define DDIM   128
#define BROWS  128           // rows per block
#define WROWS  16            // rows per wave
#define MC     64            // m-chunk
#define NCHUNK (NNODES / MC) // 16
#define THREADS 512

#define CA 0.08838834764831845f   // 1/sqrt(128+1e-8)
#define CB 0.08838834764831845f   // 1/sqrt(128+1e-9)
#define LN_EPS 1e-5f

typedef __attribute__((ext_vector_type(8))) short bf16x8;
typedef __attribute__((ext_vector_type(4))) float f32x4;
typedef __attribute__((ext_vector_type(2))) unsigned int u32x2;

// X-chunk subtile s = (d>>4)*16 + (m>>2); inner [4m][16d] bf16 row-major.
// PACKED: subtile s at ushort 64*s -> byte 128*s.
#define STILE(s) (64*(s))

// LDS layout (ushort units)
#define XB0_OFF 0                 // X-chunk buffer 0: 8192 ushorts
#define XB1_OFF 8192              // X-chunk buffer 1: 8192 ushorts
#define P_OFF   16384             // P per wave [16][72], col-swizzled: 9216
#define P_S     72
#define H_S     136               // h tile reuses [0,17408) after main loop
#define SM_TOT  25600             // 51200 bytes

// 8 tr-reads (4 dt x {lo,hi}) + internal drain. Lane addr = contiguous 8B
// within the 16-lane group's 128B window; offsets dt*2048 + {0,128}.
#define TRREAD8(T0,T1,T2,T3,T4,T5,T6,T7, AP)                                \
  asm volatile(                                                             \
    "ds_read_b64_tr_b16 %0, %8 offset:0\n\t"                                \
    "ds_read_b64_tr_b16 %1, %8 offset:128\n\t"                              \
    "ds_read_b64_tr_b16 %2, %8 offset:2048\n\t"                             \
    "ds_read_b64_tr_b16 %3, %8 offset:2176\n\t"                             \
    "ds_read_b64_tr_b16 %4, %8 offset:4096\n\t"                             \
    "ds_read_b64_tr_b16 %5, %8 offset:4224\n\t"                             \
    "ds_read_b64_tr_b16 %6, %8 offset:6144\n\t"                             \
    "ds_read_b64_tr_b16 %7, %8 offset:6272\n\t"                             \
    "s_waitcnt lgkmcnt(0)"                                                  \
    : "=&v"(T0), "=&v"(T1), "=&v"(T2), "=&v"(T3),                           \
      "=&v"(T4), "=&v"(T5), "=&v"(T6), "=&v"(T7)                            \
    : "v"(AP))

// paired f32->bf16 (RNE) via compiler path: lowers to v_cvt_pk_bf16_f32
// (m240: never hand-write the asm -- register-pressure trap).
__device__ __forceinline__ unsigned int pk2(float lo, float hi) {
  union { __hip_bfloat162 b2; unsigned int u; } cv;
  cv.b2 = __float22bfloat162_rn(make_float2(lo, hi));
  return cv.u;
}

__device__ __forceinline__ unsigned short f2bf(float f) {
  unsigned int u = __float_as_uint(f);
  u += 0x7FFFu + ((u >> 16) & 1u);     // RNE
  return (unsigned short)(u >> 16);
}

__device__ __forceinline__ bf16x8 pack8(float4 a, float4 b) {
  union { unsigned int w[4]; bf16x8 v; } u;
  u.w[0] = pk2(a.x, a.y); u.w[1] = pk2(a.z, a.w);
  u.w[2] = pk2(b.x, b.y); u.w[3] = pk2(b.z, b.w);
  return u.v;
}

__device__ __forceinline__ bf16x8 joinpair(u32x2 lo, u32x2 hi) {
  union { u32x2 d[2]; bf16x8 v; } u;
  u.d[0] = lo; u.d[1] = hi;
  return u.v;
}

__global__ __launch_bounds__(THREADS, 4)
void sdgcn_fused(const float* __restrict__ X, const float* __restrict__ A,
                 const float* __restrict__ W, const float* __restrict__ gamma,
                 const float* __restrict__ beta, float* __restrict__ Out) {
  const int bt   = blockIdx.x;                 // fast axis: blocks sharing A-slice adjacent
  const int row0 = blockIdx.y * BROWS;
  const int tid  = (int)threadIdx.x;
  const int wid  = tid >> 6;      // wave id 0..7
  const int lane = tid & 63;
  const int c    = lane & 15;     // 16-dim index within MFMA tile
  const int q    = lane >> 4;     // quad 0..3
  const int c2 = c >> 2, c3 = c & 3, q1 = q & 1, q2 = q >> 1;

  const float* Xbt = X + (size_t)bt * NNODES * DDIM;

  __shared__ __align__(128) unsigned short sm[SM_TOT];
  unsigned short* Pw = sm + P_OFF + wid * (WROWS * P_S);

  // P col-swizzle: element [row=query c][col m] stored at col ^ pswz(row).
  const int pswz = 16 * ((c >> 3) & 1);

  // ---- Q A-fragments + query sum-of-squares (fp32, LANE-LOCAL: query = c) ----
  bf16x8 qfrag[4];
  float ss = 0.f;                // ss = ||x_{query c}||^2 (diag softmax shift)
  {
    const float* qrow = Xbt + (size_t)(row0 + wid * WROWS + c) * DDIM;
#pragma unroll
    for (int ds = 0; ds < 4; ++ds) {
      const float* p = qrow + ds * 32 + q * 8;
      float4 a = *(const float4*)p;
      float4 b = *(const float4*)(p + 4);
      ss += a.x*a.x + a.y*a.y + a.z*a.z + a.w*a.w;
      ss += b.x*b.x + b.y*b.y + b.z*b.z + b.w*b.w;
      qfrag[ds] = pack8(a, b);
    }
    ss += __shfl_xor(ss, 16, 64);
    ss += __shfl_xor(ss, 32, 64);
  }

  float z_acc = 0.f;   // per-lane partial Z for query c (reduced at end)
  f32x4 Ofr[8];   // O accumulator, C/D layout: row(query)=4q+reg, col=dt*16+c
#pragma unroll
  for (int dt = 0; dt < 8; ++dt) Ofr[dt] = (f32x4){0.f, 0.f, 0.f, 0.f};

  const int grow = row0 + wid * WROWS + q * 4;   // +r gives global row for C/D rows
  const int arow = row0 + wid * WROWS + c;       // query row for A-mask / softmax

  // ---- staging map: thread -> (m = mlo + 4*(mh0+4k), float4 col sd4) ----
  const int h4  = tid & 15;
  const int mlo = (tid >> 4) & 3;          // m & 3
  const int sd4 = h4 + 16 * (wid & 1);     // float4 column 0..31
  const int mh0 = wid >> 1;                // m>>2 = mh0 + 4k
  const int sst = (sd4 >> 2) * 16 + mh0;   // subtile for k=0; +4k for others
  const int sof = 16*mlo + 4*(sd4 & 3);    // intra-subtile ushort offset

  // ---- prologue: chunk 0 -> buf0 (visible after loop's first barrier) ----
  {
    float4 stg[4];
#pragma unroll
    for (int k = 0; k < 4; ++k)
      stg[k] = *(const float4*)(Xbt + (size_t)(mlo + 4*(mh0 + 4*k)) * DDIM + sd4 * 4);
#pragma unroll
    for (int k = 0; k < 4; ++k) {
      float4 v = stg[k];
      *(uint2*)(sm + XB0_OFF + STILE(sst + 4*k) + sof) =
          make_uint2(pk2(v.x, v.y), pk2(v.z, v.w));
    }
  }

  for (int ch = 0; ch < NCHUNK; ++ch) {
    const int m0 = ch * MC;
    unsigned short* xb  = sm + ((ch & 1) ? XB1_OFF : XB0_OFF);
    unsigned short* xbn = sm + ((ch & 1) ? XB0_OFF : XB1_OFF);
    // tr-read lane base: contiguous per-lane 8B in the group's 128B window.
    const unsigned trb = (unsigned)(size_t)xb + 256u*q + 8u*c;

    __syncthreads();   // xb ready; xbn free (its ch-1 readers all arrived here)

    // ---- issue next chunk's staging loads (wait hides under QK) ----
    float4 stg[4];
    if (ch + 1 < NCHUNK) {
      const float* nx = Xbt + (size_t)(m0 + MC) * DDIM;
#pragma unroll
      for (int k = 0; k < 4; ++k)
        stg[k] = *(const float4*)(nx + (size_t)(mlo + 4*(mh0 + 4*k)) * DDIM + sd4 * 4);
    }
    // ---- prefetch adjacency row (float4; query row = c, cols 16mt+4q+r) ----
    float4 av[4];
#pragma unroll
    for (int mt = 0; mt < 4; ++mt)
      av[mt] = *(const float4*)(A + (size_t)arow * NNODES + m0 + mt*16 + 4*q);
    // ---- scores S^T = mfma(X-rows, Q): C/D row = m (16mt+4q+r), col = query c
    f32x4 S[4];
#pragma unroll
    for (int mt = 0; mt < 4; ++mt) {
      f32x4 acc = (f32x4){0.f, 0.f, 0.f, 0.f};
#pragma unroll
      for (int ds = 0; ds < 4; ++ds) {
        const bf16x8 bf = *(const bf16x8*)(xb + STILE((ds*2 + q2)*16 + mt*4 + c2)
                                              + 16*c3 + 8*q1);
        acc = __builtin_amdgcn_mfma_f32_16x16x32_bf16(bf, qfrag[ds], acc, 0, 0, 0);
      }
      S[mt] = acc;
    }
    // ---- convert + write next chunk into xbn (stg dies here, mid-body) ----
    if (ch + 1 < NCHUNK) {
#pragma unroll
      for (int k = 0; k < 4; ++k) {
        float4 v = stg[k];
        *(uint2*)(xbn + STILE(sst + 4*k) + sof) =
            make_uint2(pk2(v.x, v.y), pk2(v.z, v.w));
      }
    }
    // ---- softmax numerator (lane-local query): p = exp(S^T - ss);
    //      P[query c][m] written as uint2 4-runs, col ^ pswz ----
    float zr = 0.f;
#pragma unroll
    for (int mt = 0; mt < 4; ++mt) {
      float p0 = __expf(S[mt][0] - ss);
      float p1 = __expf(S[mt][1] - ss);
      float p2 = __expf(S[mt][2] - ss);
      float p3 = __expf(S[mt][3] - ss);
      zr += (p0 + p1) + (p2 + p3);
      *(uint2*)(Pw + c * P_S + ((mt*16 + 4*q) ^ pswz)) =
          make_uint2(pk2(p0 * av[mt].x, p1 * av[mt].y),
                     pk2(p2 * av[mt].z, p3 * av[mt].w));
    }
    z_acc += zr;
    // ---- PV: O += P·Xchunk ; A=P rows (b128, swizzle-corrected), B via HW
    //      transpose-read: 2 batches of 8 per ks, drain inside each asm ----
#pragma unroll
    for (int ks = 0; ks < 2; ++ks) {
      const bf16x8 pf = *(const bf16x8*)(Pw + c * P_S + ((ks*32 + q*8) ^ pswz));
      u32x2 t0, t1, t2, t3, t4, t5, t6, t7;
      TRREAD8(t0, t1, t2, t3, t4, t5, t6, t7, trb + 1024u*ks);
      Ofr[0] = __builtin_amdgcn_mfma_f32_16x16x32_bf16(pf, joinpair(t0, t1), Ofr[0], 0, 0, 0);
      Ofr[1] = __builtin_amdgcn_mfma_f32_16x16x32_bf16(pf, joinpair(t2, t3), Ofr[1], 0, 0, 0);
      Ofr[2] = __builtin_amdgcn_mfma_f32_16x16x32_bf16(pf, joinpair(t4, t5), Ofr[2], 0, 0, 0);
      Ofr[3] = __builtin_amdgcn_mfma_f32_16x16x32_bf16(pf, joinpair(t6, t7), Ofr[3], 0, 0, 0);
      TRREAD8(t0, t1, t2, t3, t4, t5, t6, t7, trb + 1024u*ks + 8192u);
      Ofr[4] = __builtin_amdgcn_mfma_f32_16x16x32_bf16(pf, joinpair(t0, t1), Ofr[4], 0, 0, 0);
      Ofr[5] = __builtin_amdgcn_mfma_f32_16x16x32_bf16(pf, joinpair(t2, t3), Ofr[5], 0, 0, 0);
      Ofr[6] = __builtin_amdgcn_mfma_f32_16x16x32_bf16(pf, joinpair(t4, t5), Ofr[6], 0, 0, 0);
      Ofr[7] = __builtin_amdgcn_mfma_f32_16x16x32_bf16(pf, joinpair(t6, t7), Ofr[7], 0, 0, 0);
    }
  }

  // ---- finalize Z: reduce q-group partials, then broadcast to C/D rows ----
  z_acc += __shfl_xor(z_acc, 16, 64);
  z_acc += __shfl_xor(z_acc, 32, 64);
  float zrow[4];
#pragma unroll
  for (int r = 0; r < 4; ++r)
    zrow[r] = __shfl(z_acc, (lane & 48) + ((lane & 48) >> 2) + r, 64);

  __syncthreads();   // all PV reads done; reuse X/P region for h
  // ---- h = (CA/z)*O -> bf16, per-wave LDS round-trip into A-layout (swizzled) ----
  unsigned short* Hw = sm + wid * (WROWS * H_S);
#pragma unroll
  for (int r = 0; r < 4; ++r) {
    float rinv = CA / zrow[r];
#pragma unroll
    for (int dt = 0; dt < 8; ++dt)
      Hw[(q*4 + r) * H_S + (((dt*16) ^ (16*(q>>1))) + c)] = f2bf(Ofr[dt][r] * rinv);
  }
  // ---- G = h·W^T via MFMA; B[k=d][j] = W row-reads direct from global ----
  f32x4 G[8];
#pragma unroll
  for (int jt = 0; jt < 8; ++jt) G[jt] = (f32x4){0.f, 0.f, 0.f, 0.f};
#pragma unroll
  for (int ks = 0; ks < 4; ++ks) {
    bf16x8 hf = *(const bf16x8*)(Hw + c * H_S + ((ks*32 + q*8) ^ pswz));
#pragma unroll
    for (int jt = 0; jt < 8; ++jt) {
      const float* wr = W + (size_t)(jt*16 + c) * DDIM + ks*32 + q*8;
      float4 a = *(const float4*)wr;
      float4 b = *(const float4*)(wr + 4);
      bf16x8 wf = pack8(a, b);
      G[jt] = __builtin_amdgcn_mfma_f32_16x16x32_bf16(hf, wf, G[jt], 0, 0, 0);
    }
  }
  // relu + output scale
#pragma unroll
  for (int jt = 0; jt < 8; ++jt) {
#pragma unroll
    for (int r = 0; r < 4; ++r) G[jt][r] = fmaxf(G[jt][r], 0.f) * CB;
  }
  // ---- LayerNorm over j (in-reg jt sum + 16-lane shfl), + residual, store ----
  float* Obt = Out + (size_t)bt * NNODES * DDIM;
#pragma unroll
  for (int r = 0; r < 4; ++r) {
    float s1 = 0.f, s2 = 0.f;
#pragma unroll
    for (int jt = 0; jt < 8; ++jt) { float v = G[jt][r]; s1 += v; s2 += v * v; }
#pragma unroll
    for (int off = 1; off < 16; off <<= 1) {
      s1 += __shfl_xor(s1, off, 64);
      s2 += __shfl_xor(s2, off, 64);
    }
    float mu = s1 * (1.f / 128.f);
    float va = s2 * (1.f / 128.f) - mu * mu;
    float rs = rsqrtf(va + LN_EPS);
    const float* xr = Xbt + (size_t)(grow + r) * DDIM;
    float* orow = Obt + (size_t)(grow + r) * DDIM;
#pragma unroll
    for (int jt = 0; jt < 8; ++jt) {
      int col = jt * 16 + c;
      orow[col] = (G[jt][r] - mu) * rs * gamma[col] + beta[col] + xr[col];
    }
  }
}

extern "C" void kernel_launch(void* const* d_in, const int* in_sizes, int n_in,
                              void* d_out, int out_size, void* d_ws, size_t ws_size,
                              hipStream_t stream) {
  const float* X     = (const float*)d_in[0];
  const float* A     = (const float*)d_in[1];
  const float* W     = (const float*)d_in[2];
  const float* gamma = (const float*)d_in[3];
  const float* beta  = (const float*)d_in[4];
  float* Out = (float*)d_out;
  dim3 grid(64, NNODES / BROWS);   // bt fast, 8 row-blocks slow
  hipLaunchKernelGGL(sdgcn_fused, grid, dim3(THREADS), 0, stream, X, A, W, gamma, beta, Out);
}